// Round 7
// baseline (1540.431 us; speedup 1.0000x reference)
//
#include <hip/hip_runtime.h>
#include <hip/hip_bf16.h>
#include <math.h>

#define NNODES 358
#define NN2 (358*358)
#define DIM 96
#define PP 72
#define ND 64
#define NB 8
#define NH 4
#define SEQ (NB*NNODES)

// ---- workspace layout (float offsets) ----
#define WS_WT2   0            // 96*288: W_qkv as [k][h*72+g*24+e]
#define WS_WBAR  27648        // 96
#define WS_BBAR  27744        // 1 (pad to 27752)
#define WS_PRM   27752        // SEQ*96
#define WS_DEA   302696       // SEQ*64
#define WS_DEB   485992       // SEQ*64
#define WS_DETG  669288       // 8*64*360
#define WS_AO    853616       // ao: ring = 358*72*96, full = SEQ*72*96

__device__ __forceinline__ float gelu_f(float y) {
  return 0.5f*y*(1.0f+erff(y*0.70710678118654752440f));
}

// ---------------------------------------------------------------- k0: setup
__global__ void k0_setup(const float* __restrict__ wi, const float* __restrict__ wo,
                         const float* __restrict__ bo, float* __restrict__ ws)
{
  int t = threadIdx.x;
  // W layout: ws[k*288 + h*72 + g*24 + e] = in_proj_w[(g*96 + h*24 + e)][k]
  for (int idx = t; idx < 96*288; idx += 256) {
    int k = idx / 288;
    int col = idx - k*288;
    int h = col / 72;
    int cc = col - h*72;
    int g = cc / 24, e = cc - g*24;
    ws[WS_WT2 + idx] = wi[(size_t)(g*96 + h*24 + e)*96 + k];
  }
  if (t < 96) {
    float sm = 0.0f;
    for (int d = 0; d < 96; ++d) sm += wo[d*96 + t];
    ws[WS_WBAR + t] = sm*(1.0f/96.0f);
  }
  if (t == 0) {
    float sm = 0.0f;
    for (int d = 0; d < 96; ++d) sm += bo[d];
    ws[WS_BBAR] = sm*(1.0f/96.0f);
  }
}

// ------------------------------------------- softmax + top-10 (wave-register)
__device__ void softmax_topk_row(float* lg, float* pb, float* redv,
                                 float* sc, int* sel, float* outrow)
{
  int t = threadIdx.x;
  int lane = t & 63, w = t >> 6;
  float mx = -1e30f;
  for (int m = t; m < NNODES; m += 256) mx = fmaxf(mx, lg[m]);
  for (int o = 32; o; o >>= 1) mx = fmaxf(mx, __shfl_down(mx, o, 64));
  if (lane == 0) redv[w] = mx;
  __syncthreads();
  float M = fmaxf(fmaxf(redv[0], redv[1]), fmaxf(redv[2], redv[3]));
  float ls = 0.0f;
  for (int m = t; m < NNODES; m += 256) { float e = __expf(lg[m]-M); pb[m] = e; ls += e; }
  for (int o = 32; o; o >>= 1) ls += __shfl_down(ls, o, 64);
  __syncthreads();
  if (lane == 0) redv[w] = ls;
  __syncthreads();
  float invS = 1.0f/(redv[0]+redv[1]+redv[2]+redv[3]);
  if (w == 0) {
    float vals[6];
    #pragma unroll
    for (int j = 0; j < 6; ++j) {
      int m = lane + 64*j;
      vals[j] = (m < NNODES) ? lg[m] : -1e30f;
    }
    float ss = 0.0f;
    for (int it = 0; it < 10; ++it) {
      float v = -1e30f; int idx = 0x7fffffff;
      #pragma unroll
      for (int j = 0; j < 6; ++j) {
        if (vals[j] > v) { v = vals[j]; idx = lane + 64*j; }
      }
      #pragma unroll
      for (int o = 1; o < 64; o <<= 1) {
        float ov = __shfl_xor(v, o, 64);
        int oi = __shfl_xor(idx, o, 64);
        if (ov > v || (ov == v && oi < idx)) { v = ov; idx = oi; }
      }
      if (lane == 0) sel[it] = idx;
      ss += __expf(v - M);
      #pragma unroll
      for (int j = 0; j < 6; ++j)
        if (lane + 64*j == idx) vals[j] = -1e30f;
    }
    if (lane == 0) sc[0] = ss*invS + 1e-8f;
  }
  __syncthreads();
  float dn = 1.0f/sc[0];
  for (int m = t; m < NNODES; m += 256) {
    float val = 0.0f;
    #pragma unroll
    for (int k = 0; k < 10; ++k) val = (m == sel[k]) ? pb[m]*invS*dn : val;
    outrow[m] = val;
  }
}

// --------------------------------------------------- k1: static adjacencies
__global__ void __launch_bounds__(256)
k1_static(const float* __restrict__ le1, const float* __restrict__ le2,
          const float* __restrict__ ge1, const float* __restrict__ ge2,
          const float* __restrict__ temp, float* __restrict__ outstat)
{
  __shared__ float e1[64], lg[NNODES], pb[NNODES], redv[4], sc[1];
  __shared__ int sel[10];
  int blk = blockIdx.x, t = threadIdx.x;
  int h = blk / NNODES, n = blk - h*NNODES;
  int kd; const float *e1p, *e2p; float tau;
  if (h < 2) {
    kd = 32;
    e1p = le1 + ((size_t)h*NNODES + n)*32;
    e2p = le2 + (size_t)h*32*NNODES;
    tau = fminf(fmaxf(temp[h]*2.0f, 0.1f), 5.0f);
  } else {
    kd = 64;
    e1p = ge1 + ((size_t)(h-2)*NNODES + n)*64;
    e2p = ge2 + (size_t)(h-2)*64*NNODES;
    tau = fminf(fmaxf(temp[h]*0.5f, 0.1f), 2.0f);
  }
  if (t < kd) e1[t] = e1p[t];
  __syncthreads();
  for (int m = t; m < NNODES; m += 256) {
    float s = 0.0f;
    for (int k = 0; k < kd; ++k) s += e1[k]*e2p[k*NNODES + m];
    lg[m] = fmaxf(s, 0.0f)/tau;
  }
  __syncthreads();
  softmax_topk_row(lg, pb, redv, sc, sel, outstat + (size_t)blk*NNODES);
}

// --------------------------------------- k2a: one block per sequence
// Phase 1: QKV GEMM 72x288 with 9x9 register tiles (256 thr exact fit),
//          all heads' QKV live in registers.
// Phase 2: per head: stage 72x72 -> qh/kT/vT, S, softmax, PV -> global ao.
// LDS 12960 floats = 51,840 B -> 3 blocks/CU.
#define X_STR  100
#define A2_XS  0        // 72*100; S (72x76) aliases after GEMM
#define A2_QH  7200     // 72*28
#define A2_KT  9216     // 24*76
#define A2_VT  11040    // 24*76 (ends 12864)
#define A2_WB  7200     // W chunk 16*288=4608 aliases QH/KT/VT during GEMM
#define A2_TOT 12960

__global__ void __launch_bounds__(256)
k2a_attn(const float* __restrict__ pf, const float* __restrict__ pos,
         const float* __restrict__ inb, float* __restrict__ ws,
         int s0, int aoAbs)
{
  __shared__ float L[A2_TOT];
  int blk = blockIdx.x, t = threadIdx.x;
  size_t s = (size_t)s0 + blk;
  int aoIdx = aoAbs ? (int)s : blk;
  const float* prp = pf + s*(PP*DIM);
  for (int idx = t; idx < PP*DIM; idx += 256) {
    int p = idx/DIM, e = idx - p*DIM;
    L[A2_XS + p*X_STR + e] = prp[idx];
  }
  __syncthreads();
  if (t < DIM) {                      // pf.mean over P (pre pos-enc)
    float sm = 0.0f;
    for (int p = 0; p < PP; ++p) sm += L[A2_XS + p*X_STR + t];
    ws[WS_PRM + s*DIM + t] = sm*(1.0f/72.0f);
  }
  __syncthreads();
  for (int idx = t; idx < PP*DIM; idx += 256) {
    int p = idx/DIM, e = idx - p*DIM;
    L[A2_XS + p*X_STR + e] += pos[idx];
  }
  __syncthreads();
  // ---- QKV GEMM: Y[72][288] = X[72][96] @ W[96][288]
  int rt = t >> 5, ct = t & 31;       // 8 row-tiles x 32 col-tiles
  int p0 = rt*9, c0 = ct*9;
  float acc[9][9];
  #pragma unroll
  for (int a = 0; a < 9; ++a)
    #pragma unroll
    for (int c = 0; c < 9; ++c) acc[a][c] = 0.0f;
  const float* Wall = ws + WS_WT2;
  for (int kc = 0; kc < 96; kc += 16) {
    for (int i = t; i < 16*288; i += 256)       // stage W chunk (coalesced)
      L[A2_WB + i] = Wall[(size_t)kc*288 + i];
    __syncthreads();
    #pragma unroll 2
    for (int k = 0; k < 16; ++k) {
      float xr[9], wr[9];
      #pragma unroll
      for (int a = 0; a < 9; ++a) xr[a] = L[A2_XS + (p0+a)*X_STR + kc + k];
      #pragma unroll
      for (int c = 0; c < 9; ++c) wr[c] = L[A2_WB + k*288 + c0 + c];
      #pragma unroll
      for (int a = 0; a < 9; ++a)
        #pragma unroll
        for (int c = 0; c < 9; ++c) acc[a][c] += xr[a]*wr[c];
    }
    __syncthreads();
  }
  // ---- per-head attention; x region is dead, S aliases it
  const float SC = 0.20412414523193150f;  // 1/sqrt(24)
  int hOwn = ct >> 3;                     // 72 cols = 8 col-tiles per head
  for (int h = 0; h < NH; ++h) {
    if (hOwn == h) {                      // stage this head's 72x72 from regs
      #pragma unroll
      for (int c = 0; c < 9; ++c) {
        int cc = c0 + c - h*72;           // 0..71 within head
        int g = cc/24, e = cc - g*24;
        float bias = inb[g*96 + h*24 + e];
        #pragma unroll
        for (int a = 0; a < 9; ++a) {
          float v = acc[a][c] + bias;
          int p = p0 + a;
          if (g == 0)      L[A2_QH + p*28 + e] = v*SC;
          else if (g == 1) L[A2_KT + e*76 + p] = v;
          else             L[A2_VT + e*76 + p] = v;
        }
      }
    }
    __syncthreads();
    for (int tile = t; tile < 648; tile += 256) {   // S = q k^T (base A2_XS)
      int pt = tile / 18, jt = tile - pt*18;
      int q0 = pt*2, j0 = jt*4;
      float a0=0,a1=0,a2=0,a3=0, b0=0,b1=0,b2=0,b3=0;
      #pragma unroll
      for (int d0 = 0; d0 < 24; d0 += 4) {
        float4 q0v = *(const float4*)&L[A2_QH + q0*28 + d0];
        float4 q1v = *(const float4*)&L[A2_QH + (q0+1)*28 + d0];
        #pragma unroll
        for (int dd = 0; dd < 4; ++dd) {
          float4 kv = *(const float4*)&L[A2_KT + (d0+dd)*76 + j0];
          float qa = ((const float*)&q0v)[dd];
          float qb = ((const float*)&q1v)[dd];
          a0 += qa*kv.x; a1 += qa*kv.y; a2 += qa*kv.z; a3 += qa*kv.w;
          b0 += qb*kv.x; b1 += qb*kv.y; b2 += qb*kv.z; b3 += qb*kv.w;
        }
      }
      *(float4*)&L[A2_XS + q0*76 + j0]     = make_float4(a0,a1,a2,a3);
      *(float4*)&L[A2_XS + (q0+1)*76 + j0] = make_float4(b0,b1,b2,b3);
    }
    __syncthreads();
    if (t < 72) {                       // row softmax
      float* row = &L[A2_XS + t*76];
      float mx = row[0];
      for (int j = 1; j < 72; ++j) mx = fmaxf(mx, row[j]);
      float sm = 0.0f;
      for (int j = 0; j < 72; ++j) { float e = __expf(row[j]-mx); row[j] = e; sm += e; }
      float inv = 1.0f/sm;
      for (int j = 0; j < 72; ++j) row[j] *= inv;
    }
    __syncthreads();
    if (t < 216) {                      // O = P @ V -> global ao
      int pt = t / 6, dt = t - pt*6;
      int q0 = pt*2, d0 = dt*4;
      float oa[2][4];
      #pragma unroll
      for (int a = 0; a < 2; ++a)
        #pragma unroll
        for (int dd = 0; dd < 4; ++dd) oa[a][dd] = 0.0f;
      for (int j0 = 0; j0 < 72; j0 += 4) {
        float4 pv0 = *(const float4*)&L[A2_XS + q0*76 + j0];
        float4 pv1 = *(const float4*)&L[A2_XS + (q0+1)*76 + j0];
        #pragma unroll
        for (int dd = 0; dd < 4; ++dd) {
          float4 vv = *(const float4*)&L[A2_VT + (d0+dd)*76 + j0];
          oa[0][dd] += pv0.x*vv.x + pv0.y*vv.y + pv0.z*vv.z + pv0.w*vv.w;
          oa[1][dd] += pv1.x*vv.x + pv1.y*vv.y + pv1.z*vv.z + pv1.w*vv.w;
        }
      }
      float* aob = ws + WS_AO + (size_t)aoIdx*PP*DIM;
      #pragma unroll
      for (int a = 0; a < 2; ++a)
        #pragma unroll
        for (int dd = 0; dd < 4; ++dd)
          aob[(q0+a)*DIM + h*24 + d0 + dd] = oa[a][dd];
    }
    __syncthreads();                    // protect qh/kT/vT + S rewrite next head
  }
}

// -------------------- k2b: node epilogue + dynamic encoder
#define B_AO   0      // 72 x 97
#define B_LIMP 6984
#define B_IMP  7056
#define B_WSUM 7128
#define B_NB   7224
#define B_NR   7320
#define B_WB   7416
#define B_H1   7512
#define B_G1   7640
#define B_H2   7768
#define B_TOT  7832

__global__ void __launch_bounds__(128)
k2b_node(float* __restrict__ ws,
         const float* __restrict__ wo, const float* __restrict__ bo,
         const float* __restrict__ tng, const float* __restrict__ tnb,
         const float* __restrict__ dw1, const float* __restrict__ db1,
         const float* __restrict__ dg1, const float* __restrict__ dlb1,
         const float* __restrict__ dw2, const float* __restrict__ db2,
         const float* __restrict__ dg2, const float* __restrict__ dlb2,
         int s0, int aoAbs)
{
  __shared__ float L[B_TOT];
  int blk = blockIdx.x, t = threadIdx.x;
  size_t s = (size_t)s0 + blk;
  int aoIdx = aoAbs ? (int)s : blk;
  const float* aob = ws + WS_AO + (size_t)aoIdx*PP*DIM;
  for (int idx = t; idx < PP*DIM; idx += 128) {
    int p = idx/DIM, e = idx - p*DIM;
    L[B_AO + p*97 + e] = aob[idx];
  }
  if (t < 96) L[B_WB + t] = ws[WS_WBAR + t];
  __syncthreads();
  if (t < 72) {
    float sm = 0.0f;
    for (int e = 0; e < 96; ++e) sm += L[B_AO + t*97 + e]*L[B_WB + e];
    L[B_LIMP + t] = sm + ws[WS_BBAR];
  }
  __syncthreads();
  if (t < 72) {
    float mx = L[B_LIMP];
    for (int j = 1; j < 72; ++j) mx = fmaxf(mx, L[B_LIMP+j]);
    float sm = 0.0f;
    for (int j = 0; j < 72; ++j) sm += __expf(L[B_LIMP+j]-mx);
    L[B_IMP + t] = __expf(L[B_LIMP+t]-mx)/sm;
  }
  __syncthreads();
  if (t < 96) {
    float sm = 0.0f;
    for (int p = 0; p < PP; ++p) sm += L[B_IMP+p]*L[B_AO + p*97 + t];
    L[B_WSUM + t] = sm;
  }
  __syncthreads();
  if (t < 96) {
    float sm = 0.0f;
    for (int e = 0; e < 96; ++e) sm += L[B_WSUM+e]*wo[t*96 + e];
    L[B_NB + t] = sm + bo[t] + ws[WS_PRM + s*DIM + t];
  }
  __syncthreads();
  if (t < 96) {
    float mean = 0.0f;
    for (int e = 0; e < 96; ++e) mean += L[B_NB+e];
    mean *= (1.0f/96.0f);
    float var = 0.0f;
    for (int e = 0; e < 96; ++e) { float d = L[B_NB+e]-mean; var += d*d; }
    var *= (1.0f/96.0f);
    L[B_NR + t] = (L[B_NB+t]-mean)*rsqrtf(var+1e-5f)*tng[t] + tnb[t];
  }
  __syncthreads();
  {
    float sm = 0.0f;
    for (int k = 0; k < 96; ++k) sm += L[B_NR+k]*dw1[t*96 + k];
    L[B_H1 + t] = sm + db1[t];
  }
  __syncthreads();
  {
    float mean = 0.0f; for (int e = 0; e < 128; ++e) mean += L[B_H1+e];
    mean *= (1.0f/128.0f);
    float var = 0.0f; for (int e = 0; e < 128; ++e) { float d = L[B_H1+e]-mean; var += d*d; }
    var *= (1.0f/128.0f);
    float y = (L[B_H1+t]-mean)*rsqrtf(var+1e-5f)*dg1[t] + dlb1[t];
    L[B_G1 + t] = gelu_f(y);
  }
  __syncthreads();
  if (t < 64) {
    float sm = 0.0f;
    for (int k = 0; k < 128; ++k) sm += L[B_G1+k]*dw2[t*128 + k];
    L[B_H2 + t] = sm + db2[t];
  }
  __syncthreads();
  if (t < 64) {
    float mean = 0.0f; for (int e = 0; e < 64; ++e) mean += L[B_H2+e];
    mean *= (1.0f/64.0f);
    float var = 0.0f; for (int e = 0; e < 64; ++e) { float d = L[B_H2+e]-mean; var += d*d; }
    var *= (1.0f/64.0f);
    ws[WS_DEA + s*ND + t] = (L[B_H2+t]-mean)*rsqrtf(var+1e-5f)*dg2[t] + dlb2[t];
  }
}

// ------------------------------------------------ k4t: transpose de for GNN
__global__ void k4t_transpose(float* __restrict__ ws, int deoff)
{
  int bd = blockIdx.x;
  int b = bd >> 6, d = bd & 63;
  for (int m = threadIdx.x; m < NNODES; m += 256)
    ws[WS_DETG + (size_t)bd*360 + m] = ws[deoff + ((size_t)b*NNODES + m)*ND + d];
}

// --------------------------------------------------------- k4: one GNN layer
__global__ void __launch_bounds__(256)
k4_gnn(float* __restrict__ ws, int inoff, int outoff,
       const float* __restrict__ w, const float* __restrict__ bb,
       const float* __restrict__ g, const float* __restrict__ beta)
{
  __shared__ float nrow[64], lg[NNODES], pb[NNODES], aggp[4][64], aggb[64], prj[64], redv[4];
  int blk = blockIdx.x, t = threadIdx.x;
  int b = blk / NNODES;
  if (t < 64) nrow[t] = ws[inoff + (size_t)blk*ND + t];
  __syncthreads();
  const float* dg = ws + WS_DETG + (size_t)b*64*360;
  for (int m = t; m < NNODES; m += 256) {
    float sm = 0.0f;
    for (int d = 0; d < 64; ++d) sm += nrow[d]*dg[d*360 + m];
    lg[m] = sm/0.2f;
  }
  __syncthreads();
  int lane = t & 63, wv = t >> 6;
  float mx = -1e30f;
  for (int m = t; m < NNODES; m += 256) mx = fmaxf(mx, lg[m]);
  for (int o = 32; o; o >>= 1) mx = fmaxf(mx, __shfl_down(mx, o, 64));
  if (lane == 0) redv[wv] = mx;
  __syncthreads();
  float M = fmaxf(fmaxf(redv[0],redv[1]),fmaxf(redv[2],redv[3]));
  float ls = 0.0f;
  for (int m = t; m < NNODES; m += 256) { float e = __expf(lg[m]-M); pb[m] = e; ls += e; }
  for (int o = 32; o; o >>= 1) ls += __shfl_down(ls, o, 64);
  __syncthreads();
  if (lane == 0) redv[wv] = ls;
  __syncthreads();
  float inv = 1.0f/(redv[0]+redv[1]+redv[2]+redv[3]);
  for (int m = t; m < NNODES; m += 256) pb[m] *= inv;
  __syncthreads();
  {
    int d = lane, q = wv;
    float sm = 0.0f;
    for (int m = q; m < NNODES; m += 4)
      sm += pb[m]*ws[inoff + ((size_t)(b*NNODES + m))*ND + d];
    aggp[q][d] = sm;
  }
  __syncthreads();
  if (t < 64) aggb[t] = aggp[0][t]+aggp[1][t]+aggp[2][t]+aggp[3][t];
  __syncthreads();
  if (t < 64) {
    float sm = 0.0f;
    for (int d = 0; d < 64; ++d) sm += aggb[d]*w[t*64 + d];
    prj[t] = sm + bb[t];
  }
  __syncthreads();
  if (t < 64) {
    float mean = 0.0f; for (int e = 0; e < 64; ++e) mean += prj[e];
    mean *= (1.0f/64.0f);
    float var = 0.0f; for (int e = 0; e < 64; ++e) { float d = prj[e]-mean; var += d*d; }
    var *= (1.0f/64.0f);
    float y = (prj[t]-mean)*rsqrtf(var+1e-5f)*g[t] + beta[t];
    ws[outoff + (size_t)blk*ND + t] = gelu_f(y) + nrow[t];
  }
}

// ----------------------------------------------- k5: dynamic adj + top-k
__global__ void __launch_bounds__(256)
k5_dyn(const float* __restrict__ ws, const float* __restrict__ se2,
       const float* __restrict__ temp, float* __restrict__ outdyn)
{
  __shared__ float den[64], lg[NNODES], pb[NNODES], redv[4], sc[1];
  __shared__ int sel[10];
  int blk = blockIdx.x, t = threadIdx.x;
  int n = blk % NNODES;
  int bh = blk / NNODES;
  int h = bh & 3, b = bh >> 2;
  if (t < 64) den[t] = ws[WS_DEA + ((size_t)b*NNODES + n)*ND + t];
  __syncthreads();
  float tau = fminf(fmaxf(temp[h], 0.1f), 2.0f);
  const float* sp = se2 + (size_t)h*64*NNODES;
  for (int m = t; m < NNODES; m += 256) {
    float sm = 0.0f;
    for (int d = 0; d < 64; ++d) sm += den[d]*sp[d*NNODES + m];
    lg[m] = fmaxf(sm, 0.0f)/tau;
  }
  __syncthreads();
  softmax_topk_row(lg, pb, redv, sc, sel, outdyn + (size_t)blk*NNODES);
}

// ---------------------------------- k6: fusion + edge encoder + final adj
__global__ void __launch_bounds__(256)
k6_fuse(const float* __restrict__ ws, const float* __restrict__ outstat,
        const float* __restrict__ outdyn,
        const float* __restrict__ gfw, const float* __restrict__ gfb,
        const float* __restrict__ ew1, const float* __restrict__ eb1,
        const float* __restrict__ elg, const float* __restrict__ elb,
        const float* __restrict__ ew2, const float* __restrict__ eb2,
        const float* __restrict__ ew3, const float* __restrict__ eb3,
        float* __restrict__ outfin)
{
  __shared__ float sw1[64], sb1[16], slg[16], slb[16], sw2[128], sb2[8], sw3[8], sb3[1], sfw[4];
  int blk = blockIdx.x, t = threadIdx.x;
  int b = blk / NNODES, n = blk - b*NNODES;
  if (t < 64)  sw1[t] = ew1[t];
  if (t < 16)  { sb1[t] = eb1[t]; slg[t] = elg[t]; slb[t] = elb[t]; }
  if (t < 128) sw2[t] = ew2[t];
  if (t < 8)   { sb2[t] = eb2[t]; sw3[t] = ew3[t]; }
  if (t == 0)  sb3[0] = eb3[0];
  if (t < 4) {
    const float* pm = ws + WS_PRM + (size_t)blk*DIM;
    float sm = gfb[t];
    for (int e = 0; e < DIM; ++e) sm += pm[e]*gfw[t*DIM + e];
    sfw[t] = 1.0f/(1.0f+__expf(-sm));
  }
  __syncthreads();
  size_t srow = (size_t)n*NNODES;
  for (int m = t; m < NNODES; m += 256) {
    float fu[4]; float mn = 0.0f;
    #pragma unroll
    for (int hh = 0; hh < 4; ++hh) {
      float sv = outstat[(size_t)hh*NN2 + srow + m];
      float dv = outdyn[((size_t)(b*4+hh)*NNODES + n)*NNODES + m];
      float f = (1.0f - sfw[hh])*sv + sfw[hh]*dv;
      fu[hh] = f; mn += f;
    }
    mn *= 0.25f;
    float h1[16]; float m1 = 0.0f;
    #pragma unroll
    for (int j = 0; j < 16; ++j) {
      float sm = sb1[j];
      #pragma unroll
      for (int c = 0; c < 4; ++c) sm += fu[c]*sw1[j*4+c];
      h1[j] = sm; m1 += sm;
    }
    m1 *= (1.0f/16.0f);
    float v1 = 0.0f;
    #pragma unroll
    for (int j = 0; j < 16; ++j) { float d = h1[j]-m1; v1 += d*d; }
    float is1 = rsqrtf(v1*(1.0f/16.0f) + 1e-5f);
    #pragma unroll
    for (int j = 0; j < 16; ++j) h1[j] = gelu_f((h1[j]-m1)*is1*slg[j] + slb[j]);
    float h2[8];
    #pragma unroll
    for (int i = 0; i < 8; ++i) {
      float sm = sb2[i];
      #pragma unroll
      for (int j = 0; j < 16; ++j) sm += h1[j]*sw2[i*16+j];
      h2[i] = gelu_f(sm);
    }
    float ewv = sb3[0];
    #pragma unroll
    for (int i = 0; i < 8; ++i) ewv += h2[i]*sw3[i];
    float fin = (1.0f/(1.0f+__expf(-ewv)))*mn;
    outfin[(size_t)b*NN2 + srow + m] = fin;
  }
}

// ------------------------------------------------------------- launch
extern "C" void kernel_launch(void* const* d_in, const int* in_sizes, int n_in,
                              void* d_out, int out_size, void* d_ws, size_t ws_size,
                              hipStream_t stream)
{
  const float* pf   = (const float*)d_in[0];
  const float* se2  = (const float*)d_in[1];
  const float* le1  = (const float*)d_in[2];
  const float* le2  = (const float*)d_in[3];
  const float* ge1  = (const float*)d_in[4];
  const float* ge2  = (const float*)d_in[5];
  const float* temp = (const float*)d_in[6];
  const float* wi   = (const float*)d_in[7];
  const float* inb  = (const float*)d_in[8];
  const float* wo   = (const float*)d_in[9];
  const float* bo   = (const float*)d_in[10];
  const float* tng  = (const float*)d_in[11];
  const float* tnb  = (const float*)d_in[12];
  const float* dw1  = (const float*)d_in[13];
  const float* db1  = (const float*)d_in[14];
  const float* dg1  = (const float*)d_in[15];
  const float* dlb1 = (const float*)d_in[16];
  const float* dw2  = (const float*)d_in[17];
  const float* db2  = (const float*)d_in[18];
  const float* dg2  = (const float*)d_in[19];
  const float* dlb2 = (const float*)d_in[20];
  const float* pos  = (const float*)d_in[21];
  const float* g1w  = (const float*)d_in[22];
  const float* g1b  = (const float*)d_in[23];
  const float* g1g  = (const float*)d_in[24];
  const float* g1be = (const float*)d_in[25];
  const float* g2w  = (const float*)d_in[26];
  const float* g2b  = (const float*)d_in[27];
  const float* g2g  = (const float*)d_in[28];
  const float* g2be = (const float*)d_in[29];
  const float* gfw  = (const float*)d_in[30];
  const float* gfb  = (const float*)d_in[31];
  const float* ew1  = (const float*)d_in[32];
  const float* eb1  = (const float*)d_in[33];
  const float* elg  = (const float*)d_in[34];
  const float* elb  = (const float*)d_in[35];
  const float* ew2  = (const float*)d_in[36];
  const float* eb2  = (const float*)d_in[37];
  const float* ew3  = (const float*)d_in[38];
  const float* eb3  = (const float*)d_in[39];
  float* ws = (float*)d_ws;
  float* out = (float*)d_out;
  float* outfin  = out;                            // (B,N,N)
  float* outstat = out + (size_t)NB*NN2;           // (H,N,N)
  float* outdyn  = out + (size_t)(NB+NH)*NN2;      // (B,H,N,N)

  k0_setup<<<1, 256, 0, stream>>>(wi, wo, bo, ws);
  k1_static<<<NH*NNODES, 256, 0, stream>>>(le1, le2, ge1, ge2, temp, outstat);

  size_t needFull = ((size_t)WS_AO + (size_t)SEQ*PP*DIM) * sizeof(float);
  if (ws_size >= needFull) {
    k2a_attn<<<SEQ, 256, 0, stream>>>(pf, pos, inb, ws, 0, 1);
    k2b_node<<<SEQ, 128, 0, stream>>>(ws, wo, bo, tng, tnb,
                                      dw1, db1, dg1, dlb1, dw2, db2, dg2, dlb2, 0, 1);
  } else {
    for (int B0 = 0; B0 < NB; ++B0) {
      k2a_attn<<<NNODES, 256, 0, stream>>>(pf, pos, inb, ws, B0*NNODES, 0);
      k2b_node<<<NNODES, 128, 0, stream>>>(ws, wo, bo, tng, tnb,
                                           dw1, db1, dg1, dlb1, dw2, db2, dg2, dlb2,
                                           B0*NNODES, 0);
    }
  }
  k4t_transpose<<<512, 256, 0, stream>>>(ws, WS_DEA);
  k4_gnn<<<SEQ, 256, 0, stream>>>(ws, WS_DEA, WS_DEB, g1w, g1b, g1g, g1be);
  k4t_transpose<<<512, 256, 0, stream>>>(ws, WS_DEB);
  k4_gnn<<<SEQ, 256, 0, stream>>>(ws, WS_DEB, WS_DEA, g2w, g2b, g2g, g2be);
  k5_dyn<<<NB*NH*NNODES, 256, 0, stream>>>(ws, se2, temp, outdyn);
  k6_fuse<<<SEQ, 256, 0, stream>>>(ws, outstat, outdyn, gfw, gfb,
                                   ew1, eb1, elg, elb, ew2, eb2, ew3, eb3, outfin);
}

// Round 8
// 1483.497 us; speedup vs baseline: 1.0384x; 1.0384x over previous
//
#include <hip/hip_runtime.h>
#include <hip/hip_bf16.h>
#include <math.h>

#define NNODES 358
#define NN2 (358*358)
#define DIM 96
#define PP 72
#define ND 64
#define NB 8
#define NH 4
#define SEQ (NB*NNODES)

// ---- workspace layout (float offsets) ----
#define WS_WT2   0            // 96*288: W_qkv as [k][h*72+g*24+e]
#define WS_WBAR  27648        // 96
#define WS_BBAR  27744        // 1 (pad to 27752)
#define WS_PRM   27752        // SEQ*96
#define WS_DEA   302696       // SEQ*64
#define WS_DEB   485992       // SEQ*64
#define WS_DETG  669288       // 8*64*360
#define WS_AO    853616       // ao: ring = 358*72*96, full = SEQ*72*96

__device__ __forceinline__ float gelu_f(float y) {
  return 0.5f*y*(1.0f+erff(y*0.70710678118654752440f));
}

// ---------------------------------------------------------------- k0: setup
__global__ void k0_setup(const float* __restrict__ wi, const float* __restrict__ wo,
                         const float* __restrict__ bo, float* __restrict__ ws)
{
  int t = threadIdx.x;
  // W layout: ws[k*288 + h*72 + g*24 + e] = in_proj_w[(g*96 + h*24 + e)][k]
  for (int idx = t; idx < 96*288; idx += 256) {
    int k = idx / 288;
    int col = idx - k*288;
    int h = col / 72;
    int cc = col - h*72;
    int g = cc / 24, e = cc - g*24;
    ws[WS_WT2 + idx] = wi[(size_t)(g*96 + h*24 + e)*96 + k];
  }
  if (t < 96) {
    float sm = 0.0f;
    for (int d = 0; d < 96; ++d) sm += wo[d*96 + t];
    ws[WS_WBAR + t] = sm*(1.0f/96.0f);
  }
  if (t == 0) {
    float sm = 0.0f;
    for (int d = 0; d < 96; ++d) sm += bo[d];
    ws[WS_BBAR] = sm*(1.0f/96.0f);
  }
}

// ------------------------------------------- softmax + top-10 (wave-register)
__device__ void softmax_topk_row(float* lg, float* pb, float* redv,
                                 float* sc, int* sel, float* outrow)
{
  int t = threadIdx.x;
  int lane = t & 63, w = t >> 6;
  float mx = -1e30f;
  for (int m = t; m < NNODES; m += 256) mx = fmaxf(mx, lg[m]);
  for (int o = 32; o; o >>= 1) mx = fmaxf(mx, __shfl_down(mx, o, 64));
  if (lane == 0) redv[w] = mx;
  __syncthreads();
  float M = fmaxf(fmaxf(redv[0], redv[1]), fmaxf(redv[2], redv[3]));
  float ls = 0.0f;
  for (int m = t; m < NNODES; m += 256) { float e = __expf(lg[m]-M); pb[m] = e; ls += e; }
  for (int o = 32; o; o >>= 1) ls += __shfl_down(ls, o, 64);
  __syncthreads();
  if (lane == 0) redv[w] = ls;
  __syncthreads();
  float invS = 1.0f/(redv[0]+redv[1]+redv[2]+redv[3]);
  if (w == 0) {
    float vals[6];
    #pragma unroll
    for (int j = 0; j < 6; ++j) {
      int m = lane + 64*j;
      vals[j] = (m < NNODES) ? lg[m] : -1e30f;
    }
    float ss = 0.0f;
    for (int it = 0; it < 10; ++it) {
      float v = -1e30f; int idx = 0x7fffffff;
      #pragma unroll
      for (int j = 0; j < 6; ++j) {
        if (vals[j] > v) { v = vals[j]; idx = lane + 64*j; }
      }
      #pragma unroll
      for (int o = 1; o < 64; o <<= 1) {
        float ov = __shfl_xor(v, o, 64);
        int oi = __shfl_xor(idx, o, 64);
        if (ov > v || (ov == v && oi < idx)) { v = ov; idx = oi; }
      }
      if (lane == 0) sel[it] = idx;
      ss += __expf(v - M);
      #pragma unroll
      for (int j = 0; j < 6; ++j)
        if (lane + 64*j == idx) vals[j] = -1e30f;
    }
    if (lane == 0) sc[0] = ss*invS + 1e-8f;
  }
  __syncthreads();
  float dn = 1.0f/sc[0];
  for (int m = t; m < NNODES; m += 256) {
    float val = 0.0f;
    #pragma unroll
    for (int k = 0; k < 10; ++k) val = (m == sel[k]) ? pb[m]*invS*dn : val;
    outrow[m] = val;
  }
}

// --------------------------------------------------- k1: static adjacencies
__global__ void __launch_bounds__(256)
k1_static(const float* __restrict__ le1, const float* __restrict__ le2,
          const float* __restrict__ ge1, const float* __restrict__ ge2,
          const float* __restrict__ temp, float* __restrict__ outstat)
{
  __shared__ float e1[64], lg[NNODES], pb[NNODES], redv[4], sc[1];
  __shared__ int sel[10];
  int blk = blockIdx.x, t = threadIdx.x;
  int h = blk / NNODES, n = blk - h*NNODES;
  int kd; const float *e1p, *e2p; float tau;
  if (h < 2) {
    kd = 32;
    e1p = le1 + ((size_t)h*NNODES + n)*32;
    e2p = le2 + (size_t)h*32*NNODES;
    tau = fminf(fmaxf(temp[h]*2.0f, 0.1f), 5.0f);
  } else {
    kd = 64;
    e1p = ge1 + ((size_t)(h-2)*NNODES + n)*64;
    e2p = ge2 + (size_t)(h-2)*64*NNODES;
    tau = fminf(fmaxf(temp[h]*0.5f, 0.1f), 2.0f);
  }
  if (t < kd) e1[t] = e1p[t];
  __syncthreads();
  for (int m = t; m < NNODES; m += 256) {
    float s = 0.0f;
    for (int k = 0; k < kd; ++k) s += e1[k]*e2p[k*NNODES + m];
    lg[m] = fmaxf(s, 0.0f)/tau;
  }
  __syncthreads();
  softmax_topk_row(lg, pb, redv, sc, sel, outstat + (size_t)blk*NNODES);
}

// --------------------------------------- k2a: per-(seq,head) attention
// LDS 12960 floats = 51,840 B -> 3 blocks/CU.
// W staged through LDS in 16x72 chunks aliasing the q/kT/vT region (those are
// written only AFTER the GEMM k-loop). float4 pf staging. Wave-coop softmax.
#define A_XS  0        // 72x100 x tile; S (72x76) aliases after QKV
#define A_QH  7200     // 72x28
#define A_KT  9216     // 24x76
#define A_VT  11040    // 24x76 (ends 12864)
#define A_WB  7200     // W chunk 16x72=1152, aliases A_QH during GEMM loop
#define A_TOT 12960

__global__ void __launch_bounds__(256)
k2a_attn(const float* __restrict__ pf, const float* __restrict__ pos,
         const float* __restrict__ inb, float* __restrict__ ws,
         int s0, int aoAbs)
{
  __shared__ float L[A_TOT];
  int blk = blockIdx.x, t = threadIdx.x;
  int h = blk & 3;
  int local = blk >> 2;
  size_t s = (size_t)s0 + local;
  int aoIdx = aoAbs ? (int)s : local;
  // ---- stage x (float4)
  const float4* prp4 = (const float4*)(pf + s*(PP*DIM));
  for (int i = t; i < PP*DIM/4; i += 256) {
    int p = i / 24, e4 = (i - p*24)*4;
    *(float4*)&L[A_XS + p*100 + e4] = prp4[i];
  }
  __syncthreads();
  if (h == 0 && t < DIM) {            // pf.mean over P (pre pos-enc)
    float sm = 0.0f;
    for (int p = 0; p < PP; ++p) sm += L[A_XS + p*100 + t];
    ws[WS_PRM + s*DIM + t] = sm*(1.0f/72.0f);
  }
  __syncthreads();
  const float4* pos4 = (const float4*)pos;
  for (int i = t; i < PP*DIM/4; i += 256) {
    int p = i / 24, e4 = (i - p*24)*4;
    float4 pv = pos4[i];
    float* dst = &L[A_XS + p*100 + e4];
    dst[0] += pv.x; dst[1] += pv.y; dst[2] += pv.z; dst[3] += pv.w;
  }
  __syncthreads();
  // ---- QKV GEMM (this head): Y[72][72] = X[72][96] @ Wh[96][72]
  const float* Wh = ws + WS_WT2 + h*72;   // row k at Wh[k*288 + e]
  int pt = t / 12, jt = t - pt*12;        // 18 row-tiles(4) x 12 col-tiles(6)
  int p0 = pt*4, gc0 = jt*6;
  float acc[4][6];
  #pragma unroll
  for (int a = 0; a < 4; ++a)
    #pragma unroll
    for (int c = 0; c < 6; ++c) acc[a][c] = 0.0f;
  for (int kc = 0; kc < 96; kc += 16) {
    for (int i = t; i < 16*72; i += 256) {   // stage W chunk (coalesced)
      int r = i / 72, e = i - r*72;
      L[A_WB + i] = Wh[(size_t)(kc + r)*288 + e];
    }
    __syncthreads();
    if (t < 216) {
      #pragma unroll
      for (int k4 = 0; k4 < 16; k4 += 4) {
        float4 xv[4];
        #pragma unroll
        for (int a = 0; a < 4; ++a)
          xv[a] = *(const float4*)&L[A_XS + (p0+a)*100 + kc + k4];
        #pragma unroll
        for (int kk = 0; kk < 4; ++kk) {
          const float* wr = &L[A_WB + (k4+kk)*72 + gc0];
          float2 w01 = *(const float2*)(wr);
          float2 w23 = *(const float2*)(wr + 2);
          float2 w45 = *(const float2*)(wr + 4);
          float wv[6] = {w01.x, w01.y, w23.x, w23.y, w45.x, w45.y};
          #pragma unroll
          for (int a = 0; a < 4; ++a) {
            float xa = ((const float*)&xv[a])[kk];
            #pragma unroll
            for (int c = 0; c < 6; ++c) acc[a][c] += xa*wv[c];
          }
        }
      }
    }
    __syncthreads();
  }
  // ---- write q/kT/vT (wbuf dead now)
  const float SC = 0.20412414523193150f;  // 1/sqrt(24)
  if (t < 216) {
    int g = jt >> 2;          // 0=q,1=k,2=v
    int c0 = (jt & 3)*6;
    #pragma unroll
    for (int c = 0; c < 6; ++c) {
      int e = c0 + c;
      float bias = inb[g*96 + h*24 + e];
      #pragma unroll
      for (int a = 0; a < 4; ++a) {
        float v = acc[a][c] + bias;
        int p = p0 + a;
        if (g == 0)      L[A_QH + p*28 + e] = v*SC;
        else if (g == 1) L[A_KT + e*76 + p] = v;
        else             L[A_VT + e*76 + p] = v;
      }
    }
  }
  __syncthreads();
  // ---- S = q k^T (aliases XS, stride 76)
  for (int tile = t; tile < 648; tile += 256) {
    int qt = tile / 18, jt2 = tile - qt*18;
    int q0 = qt*2, j0 = jt2*4;
    float a0=0,a1=0,a2=0,a3=0, b0=0,b1=0,b2=0,b3=0;
    #pragma unroll
    for (int d0 = 0; d0 < 24; d0 += 4) {
      float4 q0v = *(const float4*)&L[A_QH + q0*28 + d0];
      float4 q1v = *(const float4*)&L[A_QH + (q0+1)*28 + d0];
      #pragma unroll
      for (int dd = 0; dd < 4; ++dd) {
        float4 kv = *(const float4*)&L[A_KT + (d0+dd)*76 + j0];
        float qa = ((const float*)&q0v)[dd];
        float qb = ((const float*)&q1v)[dd];
        a0 += qa*kv.x; a1 += qa*kv.y; a2 += qa*kv.z; a3 += qa*kv.w;
        b0 += qb*kv.x; b1 += qb*kv.y; b2 += qb*kv.z; b3 += qb*kv.w;
      }
    }
    *(float4*)&L[A_XS + q0*76 + j0]     = make_float4(a0,a1,a2,a3);
    *(float4*)&L[A_XS + (q0+1)*76 + j0] = make_float4(b0,b1,b2,b3);
  }
  __syncthreads();
  // ---- wave-cooperative row softmax (conflict-free, all 4 waves)
  {
    int lane = t & 63, w = t >> 6;
    for (int r = w; r < PP; r += 4) {
      float* row = &L[A_XS + r*76];
      float v0 = row[lane];
      float v1 = (lane < 8) ? row[64 + lane] : -1e30f;
      float mx = fmaxf(v0, v1);
      #pragma unroll
      for (int o = 32; o; o >>= 1) mx = fmaxf(mx, __shfl_xor(mx, o, 64));
      float e0 = __expf(v0 - mx);
      float e1 = (lane < 8) ? __expf(v1 - mx) : 0.0f;
      float sm = e0 + e1;
      #pragma unroll
      for (int o = 32; o; o >>= 1) sm += __shfl_xor(sm, o, 64);
      float inv = 1.0f/sm;
      row[lane] = e0*inv;
      if (lane < 8) row[64 + lane] = e1*inv;
    }
  }
  __syncthreads();
  // ---- O = P @ V -> global ao
  if (t < 216) {
    int qt = t / 6, dt = t - qt*6;
    int q0 = qt*2, d0 = dt*4;
    float oa[2][4];
    #pragma unroll
    for (int a = 0; a < 2; ++a)
      #pragma unroll
      for (int dd = 0; dd < 4; ++dd) oa[a][dd] = 0.0f;
    for (int j0 = 0; j0 < 72; j0 += 4) {
      float4 pv0 = *(const float4*)&L[A_XS + q0*76 + j0];
      float4 pv1 = *(const float4*)&L[A_XS + (q0+1)*76 + j0];
      #pragma unroll
      for (int dd = 0; dd < 4; ++dd) {
        float4 vv = *(const float4*)&L[A_VT + (d0+dd)*76 + j0];
        oa[0][dd] += pv0.x*vv.x + pv0.y*vv.y + pv0.z*vv.z + pv0.w*vv.w;
        oa[1][dd] += pv1.x*vv.x + pv1.y*vv.y + pv1.z*vv.z + pv1.w*vv.w;
      }
    }
    float* aob = ws + WS_AO + (size_t)aoIdx*PP*DIM;
    #pragma unroll
    for (int a = 0; a < 2; ++a)
      #pragma unroll
      for (int dd = 0; dd < 4; ++dd)
        aob[(q0+a)*DIM + h*24 + d0 + dd] = oa[a][dd];
  }
}

// -------------------- k2b: node epilogue + dynamic encoder
#define B_AO   0      // 72 x 97
#define B_LIMP 6984
#define B_IMP  7056
#define B_WSUM 7128
#define B_NB   7224
#define B_NR   7320
#define B_WB   7416
#define B_H1   7512
#define B_G1   7640
#define B_H2   7768
#define B_TOT  7832

__global__ void __launch_bounds__(128)
k2b_node(float* __restrict__ ws,
         const float* __restrict__ wo, const float* __restrict__ bo,
         const float* __restrict__ tng, const float* __restrict__ tnb,
         const float* __restrict__ dw1, const float* __restrict__ db1,
         const float* __restrict__ dg1, const float* __restrict__ dlb1,
         const float* __restrict__ dw2, const float* __restrict__ db2,
         const float* __restrict__ dg2, const float* __restrict__ dlb2,
         int s0, int aoAbs)
{
  __shared__ float L[B_TOT];
  int blk = blockIdx.x, t = threadIdx.x;
  size_t s = (size_t)s0 + blk;
  int aoIdx = aoAbs ? (int)s : blk;
  const float* aob = ws + WS_AO + (size_t)aoIdx*PP*DIM;
  for (int idx = t; idx < PP*DIM; idx += 128) {
    int p = idx/DIM, e = idx - p*DIM;
    L[B_AO + p*97 + e] = aob[idx];
  }
  if (t < 96) L[B_WB + t] = ws[WS_WBAR + t];
  __syncthreads();
  if (t < 72) {
    float sm = 0.0f;
    for (int e = 0; e < 96; ++e) sm += L[B_AO + t*97 + e]*L[B_WB + e];
    L[B_LIMP + t] = sm + ws[WS_BBAR];
  }
  __syncthreads();
  if (t < 72) {
    float mx = L[B_LIMP];
    for (int j = 1; j < 72; ++j) mx = fmaxf(mx, L[B_LIMP+j]);
    float sm = 0.0f;
    for (int j = 0; j < 72; ++j) sm += __expf(L[B_LIMP+j]-mx);
    L[B_IMP + t] = __expf(L[B_LIMP+t]-mx)/sm;
  }
  __syncthreads();
  if (t < 96) {
    float sm = 0.0f;
    for (int p = 0; p < PP; ++p) sm += L[B_IMP+p]*L[B_AO + p*97 + t];
    L[B_WSUM + t] = sm;
  }
  __syncthreads();
  if (t < 96) {
    float sm = 0.0f;
    for (int e = 0; e < 96; ++e) sm += L[B_WSUM+e]*wo[t*96 + e];
    L[B_NB + t] = sm + bo[t] + ws[WS_PRM + s*DIM + t];
  }
  __syncthreads();
  if (t < 96) {
    float mean = 0.0f;
    for (int e = 0; e < 96; ++e) mean += L[B_NB+e];
    mean *= (1.0f/96.0f);
    float var = 0.0f;
    for (int e = 0; e < 96; ++e) { float d = L[B_NB+e]-mean; var += d*d; }
    var *= (1.0f/96.0f);
    L[B_NR + t] = (L[B_NB+t]-mean)*rsqrtf(var+1e-5f)*tng[t] + tnb[t];
  }
  __syncthreads();
  {
    float sm = 0.0f;
    for (int k = 0; k < 96; ++k) sm += L[B_NR+k]*dw1[t*96 + k];
    L[B_H1 + t] = sm + db1[t];
  }
  __syncthreads();
  {
    float mean = 0.0f; for (int e = 0; e < 128; ++e) mean += L[B_H1+e];
    mean *= (1.0f/128.0f);
    float var = 0.0f; for (int e = 0; e < 128; ++e) { float d = L[B_H1+e]-mean; var += d*d; }
    var *= (1.0f/128.0f);
    float y = (L[B_H1+t]-mean)*rsqrtf(var+1e-5f)*dg1[t] + dlb1[t];
    L[B_G1 + t] = gelu_f(y);
  }
  __syncthreads();
  if (t < 64) {
    float sm = 0.0f;
    for (int k = 0; k < 128; ++k) sm += L[B_G1+k]*dw2[t*128 + k];
    L[B_H2 + t] = sm + db2[t];
  }
  __syncthreads();
  if (t < 64) {
    float mean = 0.0f; for (int e = 0; e < 64; ++e) mean += L[B_H2+e];
    mean *= (1.0f/64.0f);
    float var = 0.0f; for (int e = 0; e < 64; ++e) { float d = L[B_H2+e]-mean; var += d*d; }
    var *= (1.0f/64.0f);
    ws[WS_DEA + s*ND + t] = (L[B_H2+t]-mean)*rsqrtf(var+1e-5f)*dg2[t] + dlb2[t];
  }
}

// ------------------------------------------------ k4t: transpose de for GNN
__global__ void k4t_transpose(float* __restrict__ ws, int deoff)
{
  int bd = blockIdx.x;
  int b = bd >> 6, d = bd & 63;
  for (int m = threadIdx.x; m < NNODES; m += 256)
    ws[WS_DETG + (size_t)bd*360 + m] = ws[deoff + ((size_t)b*NNODES + m)*ND + d];
}

// --------------------------------------------------------- k4: one GNN layer
__global__ void __launch_bounds__(256)
k4_gnn(float* __restrict__ ws, int inoff, int outoff,
       const float* __restrict__ w, const float* __restrict__ bb,
       const float* __restrict__ g, const float* __restrict__ beta)
{
  __shared__ float nrow[64], lg[NNODES], pb[NNODES], aggp[4][64], aggb[64], prj[64], redv[4];
  int blk = blockIdx.x, t = threadIdx.x;
  int b = blk / NNODES;
  if (t < 64) nrow[t] = ws[inoff + (size_t)blk*ND + t];
  __syncthreads();
  const float* dg = ws + WS_DETG + (size_t)b*64*360;
  for (int m = t; m < NNODES; m += 256) {
    float sm = 0.0f;
    for (int d = 0; d < 64; ++d) sm += nrow[d]*dg[d*360 + m];
    lg[m] = sm/0.2f;
  }
  __syncthreads();
  int lane = t & 63, wv = t >> 6;
  float mx = -1e30f;
  for (int m = t; m < NNODES; m += 256) mx = fmaxf(mx, lg[m]);
  for (int o = 32; o; o >>= 1) mx = fmaxf(mx, __shfl_down(mx, o, 64));
  if (lane == 0) redv[wv] = mx;
  __syncthreads();
  float M = fmaxf(fmaxf(redv[0],redv[1]),fmaxf(redv[2],redv[3]));
  float ls = 0.0f;
  for (int m = t; m < NNODES; m += 256) { float e = __expf(lg[m]-M); pb[m] = e; ls += e; }
  for (int o = 32; o; o >>= 1) ls += __shfl_down(ls, o, 64);
  __syncthreads();
  if (lane == 0) redv[wv] = ls;
  __syncthreads();
  float inv = 1.0f/(redv[0]+redv[1]+redv[2]+redv[3]);
  for (int m = t; m < NNODES; m += 256) pb[m] *= inv;
  __syncthreads();
  {
    int d = lane, q = wv;
    float sm = 0.0f;
    for (int m = q; m < NNODES; m += 4)
      sm += pb[m]*ws[inoff + ((size_t)(b*NNODES + m))*ND + d];
    aggp[q][d] = sm;
  }
  __syncthreads();
  if (t < 64) aggb[t] = aggp[0][t]+aggp[1][t]+aggp[2][t]+aggp[3][t];
  __syncthreads();
  if (t < 64) {
    float sm = 0.0f;
    for (int d = 0; d < 64; ++d) sm += aggb[d]*w[t*64 + d];
    prj[t] = sm + bb[t];
  }
  __syncthreads();
  if (t < 64) {
    float mean = 0.0f; for (int e = 0; e < 64; ++e) mean += prj[e];
    mean *= (1.0f/64.0f);
    float var = 0.0f; for (int e = 0; e < 64; ++e) { float d = prj[e]-mean; var += d*d; }
    var *= (1.0f/64.0f);
    float y = (prj[t]-mean)*rsqrtf(var+1e-5f)*g[t] + beta[t];
    ws[outoff + (size_t)blk*ND + t] = gelu_f(y) + nrow[t];
  }
}

// ----------------------------------------------- k5: dynamic adj + top-k
__global__ void __launch_bounds__(256)
k5_dyn(const float* __restrict__ ws, const float* __restrict__ se2,
       const float* __restrict__ temp, float* __restrict__ outdyn)
{
  __shared__ float den[64], lg[NNODES], pb[NNODES], redv[4], sc[1];
  __shared__ int sel[10];
  int blk = blockIdx.x, t = threadIdx.x;
  int n = blk % NNODES;
  int bh = blk / NNODES;
  int h = bh & 3, b = bh >> 2;
  if (t < 64) den[t] = ws[WS_DEA + ((size_t)b*NNODES + n)*ND + t];
  __syncthreads();
  float tau = fminf(fmaxf(temp[h], 0.1f), 2.0f);
  const float* sp = se2 + (size_t)h*64*NNODES;
  for (int m = t; m < NNODES; m += 256) {
    float sm = 0.0f;
    for (int d = 0; d < 64; ++d) sm += den[d]*sp[d*NNODES + m];
    lg[m] = fmaxf(sm, 0.0f)/tau;
  }
  __syncthreads();
  softmax_topk_row(lg, pb, redv, sc, sel, outdyn + (size_t)blk*NNODES);
}

// ---------------------------------- k6: fusion + edge encoder + final adj
__global__ void __launch_bounds__(256)
k6_fuse(const float* __restrict__ ws, const float* __restrict__ outstat,
        const float* __restrict__ outdyn,
        const float* __restrict__ gfw, const float* __restrict__ gfb,
        const float* __restrict__ ew1, const float* __restrict__ eb1,
        const float* __restrict__ elg, const float* __restrict__ elb,
        const float* __restrict__ ew2, const float* __restrict__ eb2,
        const float* __restrict__ ew3, const float* __restrict__ eb3,
        float* __restrict__ outfin)
{
  __shared__ float sw1[64], sb1[16], slg[16], slb[16], sw2[128], sb2[8], sw3[8], sb3[1], sfw[4];
  int blk = blockIdx.x, t = threadIdx.x;
  int b = blk / NNODES, n = blk - b*NNODES;
  if (t < 64)  sw1[t] = ew1[t];
  if (t < 16)  { sb1[t] = eb1[t]; slg[t] = elg[t]; slb[t] = elb[t]; }
  if (t < 128) sw2[t] = ew2[t];
  if (t < 8)   { sb2[t] = eb2[t]; sw3[t] = ew3[t]; }
  if (t == 0)  sb3[0] = eb3[0];
  if (t < 4) {
    const float* pm = ws + WS_PRM + (size_t)blk*DIM;
    float sm = gfb[t];
    for (int e = 0; e < DIM; ++e) sm += pm[e]*gfw[t*DIM + e];
    sfw[t] = 1.0f/(1.0f+__expf(-sm));
  }
  __syncthreads();
  size_t srow = (size_t)n*NNODES;
  for (int m = t; m < NNODES; m += 256) {
    float fu[4]; float mn = 0.0f;
    #pragma unroll
    for (int hh = 0; hh < 4; ++hh) {
      float sv = outstat[(size_t)hh*NN2 + srow + m];
      float dv = outdyn[((size_t)(b*4+hh)*NNODES + n)*NNODES + m];
      float f = (1.0f - sfw[hh])*sv + sfw[hh]*dv;
      fu[hh] = f; mn += f;
    }
    mn *= 0.25f;
    float h1[16]; float m1 = 0.0f;
    #pragma unroll
    for (int j = 0; j < 16; ++j) {
      float sm = sb1[j];
      #pragma unroll
      for (int c = 0; c < 4; ++c) sm += fu[c]*sw1[j*4+c];
      h1[j] = sm; m1 += sm;
    }
    m1 *= (1.0f/16.0f);
    float v1 = 0.0f;
    #pragma unroll
    for (int j = 0; j < 16; ++j) { float d = h1[j]-m1; v1 += d*d; }
    float is1 = rsqrtf(v1*(1.0f/16.0f) + 1e-5f);
    #pragma unroll
    for (int j = 0; j < 16; ++j) h1[j] = gelu_f((h1[j]-m1)*is1*slg[j] + slb[j]);
    float h2[8];
    #pragma unroll
    for (int i = 0; i < 8; ++i) {
      float sm = sb2[i];
      #pragma unroll
      for (int j = 0; j < 16; ++j) sm += h1[j]*sw2[i*16+j];
      h2[i] = gelu_f(sm);
    }
    float ewv = sb3[0];
    #pragma unroll
    for (int i = 0; i < 8; ++i) ewv += h2[i]*sw3[i];
    float fin = (1.0f/(1.0f+__expf(-ewv)))*mn;
    outfin[(size_t)b*NN2 + srow + m] = fin;
  }
}

// ------------------------------------------------------------- launch
extern "C" void kernel_launch(void* const* d_in, const int* in_sizes, int n_in,
                              void* d_out, int out_size, void* d_ws, size_t ws_size,
                              hipStream_t stream)
{
  const float* pf   = (const float*)d_in[0];
  const float* se2  = (const float*)d_in[1];
  const float* le1  = (const float*)d_in[2];
  const float* le2  = (const float*)d_in[3];
  const float* ge1  = (const float*)d_in[4];
  const float* ge2  = (const float*)d_in[5];
  const float* temp = (const float*)d_in[6];
  const float* wi   = (const float*)d_in[7];
  const float* inb  = (const float*)d_in[8];
  const float* wo   = (const float*)d_in[9];
  const float* bo   = (const float*)d_in[10];
  const float* tng  = (const float*)d_in[11];
  const float* tnb  = (const float*)d_in[12];
  const float* dw1  = (const float*)d_in[13];
  const float* db1  = (const float*)d_in[14];
  const float* dg1  = (const float*)d_in[15];
  const float* dlb1 = (const float*)d_in[16];
  const float* dw2  = (const float*)d_in[17];
  const float* db2  = (const float*)d_in[18];
  const float* dg2  = (const float*)d_in[19];
  const float* dlb2 = (const float*)d_in[20];
  const float* pos  = (const float*)d_in[21];
  const float* g1w  = (const float*)d_in[22];
  const float* g1b  = (const float*)d_in[23];
  const float* g1g  = (const float*)d_in[24];
  const float* g1be = (const float*)d_in[25];
  const float* g2w  = (const float*)d_in[26];
  const float* g2b  = (const float*)d_in[27];
  const float* g2g  = (const float*)d_in[28];
  const float* g2be = (const float*)d_in[29];
  const float* gfw  = (const float*)d_in[30];
  const float* gfb  = (const float*)d_in[31];
  const float* ew1  = (const float*)d_in[32];
  const float* eb1  = (const float*)d_in[33];
  const float* elg  = (const float*)d_in[34];
  const float* elb  = (const float*)d_in[35];
  const float* ew2  = (const float*)d_in[36];
  const float* eb2  = (const float*)d_in[37];
  const float* ew3  = (const float*)d_in[38];
  const float* eb3  = (const float*)d_in[39];
  float* ws = (float*)d_ws;
  float* out = (float*)d_out;
  float* outfin  = out;                            // (B,N,N)
  float* outstat = out + (size_t)NB*NN2;           // (H,N,N)
  float* outdyn  = out + (size_t)(NB+NH)*NN2;      // (B,H,N,N)

  k0_setup<<<1, 256, 0, stream>>>(wi, wo, bo, ws);
  k1_static<<<NH*NNODES, 256, 0, stream>>>(le1, le2, ge1, ge2, temp, outstat);

  size_t needFull = ((size_t)WS_AO + (size_t)SEQ*PP*DIM) * sizeof(float);
  if (ws_size >= needFull) {
    k2a_attn<<<SEQ*NH, 256, 0, stream>>>(pf, pos, inb, ws, 0, 1);
    k2b_node<<<SEQ, 128, 0, stream>>>(ws, wo, bo, tng, tnb,
                                      dw1, db1, dg1, dlb1, dw2, db2, dg2, dlb2, 0, 1);
  } else {
    for (int B0 = 0; B0 < NB; ++B0) {
      k2a_attn<<<NNODES*NH, 256, 0, stream>>>(pf, pos, inb, ws, B0*NNODES, 0);
      k2b_node<<<NNODES, 128, 0, stream>>>(ws, wo, bo, tng, tnb,
                                           dw1, db1, dg1, dlb1, dw2, db2, dg2, dlb2,
                                           B0*NNODES, 0);
    }
  }
  k4t_transpose<<<512, 256, 0, stream>>>(ws, WS_DEA);
  k4_gnn<<<SEQ, 256, 0, stream>>>(ws, WS_DEA, WS_DEB, g1w, g1b, g1g, g1be);
  k4t_transpose<<<512, 256, 0, stream>>>(ws, WS_DEB);
  k4_gnn<<<SEQ, 256, 0, stream>>>(ws, WS_DEB, WS_DEA, g2w, g2b, g2g, g2be);
  k5_dyn<<<NB*NH*NNODES, 256, 0, stream>>>(ws, se2, temp, outdyn);
  k6_fuse<<<SEQ, 256, 0, stream>>>(ws, outstat, outdyn, gfw, gfb,
                                   ew1, eb1, elg, elb, ew2, eb2, ew3, eb3, outfin);
}

// Round 9
// 1308.489 us; speedup vs baseline: 1.1773x; 1.1337x over previous
//
#include <hip/hip_runtime.h>
#include <hip/hip_bf16.h>
#include <math.h>

#define NNODES 358
#define NN2 (358*358)
#define DIM 96
#define PP 72
#define ND 64
#define NB 8
#define NH 4
#define SEQ (NB*NNODES)

// ---- workspace layout (float offsets) ----
#define WS_WT2   0            // 96*288: W_qkv as [k][h*72+g*24+e]
#define WS_WBAR  27648        // 96
#define WS_BBAR  27744        // 1
#define WS_PSM   27752        // 96 : column mean of pos_enc
#define WS_PRM   27848        // SEQ*96
#define WS_DEA   302792       // SEQ*64
#define WS_DEB   486088       // SEQ*64
#define WS_DETG  669384       // 8*64*360
#define WS_AO    853704       // ao: ring = 358*72*96, full = SEQ*72*96

__device__ __forceinline__ float gelu_f(float y) {
  return 0.5f*y*(1.0f+erff(y*0.70710678118654752440f));
}

// ---------------------------------------------------------------- k0: setup
__global__ void k0_setup(const float* __restrict__ wi, const float* __restrict__ wo,
                         const float* __restrict__ bo, const float* __restrict__ pos,
                         float* __restrict__ ws)
{
  int t = threadIdx.x;
  // W layout: ws[k*288 + h*72 + g*24 + e] = in_proj_w[(g*96 + h*24 + e)][k]
  for (int idx = t; idx < 96*288; idx += 256) {
    int k = idx / 288;
    int col = idx - k*288;
    int h = col / 72;
    int cc = col - h*72;
    int g = cc / 24, e = cc - g*24;
    ws[WS_WT2 + idx] = wi[(size_t)(g*96 + h*24 + e)*96 + k];
  }
  if (t < 96) {
    float sm = 0.0f;
    for (int d = 0; d < 96; ++d) sm += wo[d*96 + t];
    ws[WS_WBAR + t] = sm*(1.0f/96.0f);
  }
  if (t == 0) {
    float sm = 0.0f;
    for (int d = 0; d < 96; ++d) sm += bo[d];
    ws[WS_BBAR] = sm*(1.0f/96.0f);
  }
  if (t < 96) {   // column mean of pos_enc (for prm reconstruction)
    float sm = 0.0f;
    for (int p = 0; p < PP; ++p) sm += pos[p*DIM + t];
    ws[WS_PSM + t] = sm*(1.0f/72.0f);
  }
}

// ------------------------------------------- softmax + top-10 (wave-register)
__device__ void softmax_topk_row(float* lg, float* pb, float* redv,
                                 float* sc, int* sel, float* outrow)
{
  int t = threadIdx.x;
  int lane = t & 63, w = t >> 6;
  float mx = -1e30f;
  for (int m = t; m < NNODES; m += 256) mx = fmaxf(mx, lg[m]);
  for (int o = 32; o; o >>= 1) mx = fmaxf(mx, __shfl_down(mx, o, 64));
  if (lane == 0) redv[w] = mx;
  __syncthreads();
  float M = fmaxf(fmaxf(redv[0], redv[1]), fmaxf(redv[2], redv[3]));
  float ls = 0.0f;
  for (int m = t; m < NNODES; m += 256) { float e = __expf(lg[m]-M); pb[m] = e; ls += e; }
  for (int o = 32; o; o >>= 1) ls += __shfl_down(ls, o, 64);
  __syncthreads();
  if (lane == 0) redv[w] = ls;
  __syncthreads();
  float invS = 1.0f/(redv[0]+redv[1]+redv[2]+redv[3]);
  if (w == 0) {
    float vals[6];
    #pragma unroll
    for (int j = 0; j < 6; ++j) {
      int m = lane + 64*j;
      vals[j] = (m < NNODES) ? lg[m] : -1e30f;
    }
    float ss = 0.0f;
    for (int it = 0; it < 10; ++it) {
      float v = -1e30f; int idx = 0x7fffffff;
      #pragma unroll
      for (int j = 0; j < 6; ++j) {
        if (vals[j] > v) { v = vals[j]; idx = lane + 64*j; }
      }
      #pragma unroll
      for (int o = 1; o < 64; o <<= 1) {
        float ov = __shfl_xor(v, o, 64);
        int oi = __shfl_xor(idx, o, 64);
        if (ov > v || (ov == v && oi < idx)) { v = ov; idx = oi; }
      }
      if (lane == 0) sel[it] = idx;
      ss += __expf(v - M);
      #pragma unroll
      for (int j = 0; j < 6; ++j)
        if (lane + 64*j == idx) vals[j] = -1e30f;
    }
    if (lane == 0) sc[0] = ss*invS + 1e-8f;
  }
  __syncthreads();
  float dn = 1.0f/sc[0];
  for (int m = t; m < NNODES; m += 256) {
    float val = 0.0f;
    #pragma unroll
    for (int k = 0; k < 10; ++k) val = (m == sel[k]) ? pb[m]*invS*dn : val;
    outrow[m] = val;
  }
}

// --------------------------------------------------- k1: static adjacencies
__global__ void __launch_bounds__(256)
k1_static(const float* __restrict__ le1, const float* __restrict__ le2,
          const float* __restrict__ ge1, const float* __restrict__ ge2,
          const float* __restrict__ temp, float* __restrict__ outstat)
{
  __shared__ float e1[64], lg[NNODES], pb[NNODES], redv[4], sc[1];
  __shared__ int sel[10];
  int blk = blockIdx.x, t = threadIdx.x;
  int h = blk / NNODES, n = blk - h*NNODES;
  int kd; const float *e1p, *e2p; float tau;
  if (h < 2) {
    kd = 32;
    e1p = le1 + ((size_t)h*NNODES + n)*32;
    e2p = le2 + (size_t)h*32*NNODES;
    tau = fminf(fmaxf(temp[h]*2.0f, 0.1f), 5.0f);
  } else {
    kd = 64;
    e1p = ge1 + ((size_t)(h-2)*NNODES + n)*64;
    e2p = ge2 + (size_t)(h-2)*64*NNODES;
    tau = fminf(fmaxf(temp[h]*0.5f, 0.1f), 2.0f);
  }
  if (t < kd) e1[t] = e1p[t];
  __syncthreads();
  for (int m = t; m < NNODES; m += 256) {
    float s = 0.0f;
    for (int k = 0; k < kd; ++k) s += e1[k]*e2p[k*NNODES + m];
    lg[m] = fmaxf(s, 0.0f)/tau;
  }
  __syncthreads();
  softmax_topk_row(lg, pb, redv, sc, sel, outstat + (size_t)blk*NNODES);
}

// --------------------------------------- k2a: per-(seq,head) attention
// Round-6 proven structure (W per-thread global loads, no extra barriers)
// + fused pf+pos float4 staging (saves 2 barriers + one LDS pass)
// + wave-cooperative softmax. LDS 12960 floats = 51,840 B -> 3 blocks/CU.
#define A_XS  0        // 72x100 x tile; S (72x76) aliases after QKV
#define A_QH  7200     // 72x28
#define A_KT  9216     // 24x76
#define A_VT  11040    // 24x76 (ends 12864)
#define A_TOT 12960

__global__ void __launch_bounds__(256)
k2a_attn(const float* __restrict__ pf, const float* __restrict__ pos,
         const float* __restrict__ inb, float* __restrict__ ws,
         int s0, int aoAbs)
{
  __shared__ float L[A_TOT];
  int blk = blockIdx.x, t = threadIdx.x;
  int h = blk & 3;
  int local = blk >> 2;
  size_t s = (size_t)s0 + local;
  int aoIdx = aoAbs ? (int)s : local;
  // ---- stage x = pf + pos (fused, float4)
  const float4* prp4 = (const float4*)(pf + s*(PP*DIM));
  const float4* pos4 = (const float4*)pos;
  for (int i = t; i < PP*DIM/4; i += 256) {
    int p = i / 24, e4 = (i - p*24)*4;
    float4 a = prp4[i], b = pos4[i];
    a.x += b.x; a.y += b.y; a.z += b.z; a.w += b.w;
    *(float4*)&L[A_XS + p*100 + e4] = a;
  }
  __syncthreads();
  if (h == 0 && t < DIM) {  // prm = colmean(pf+pos) - posmean  (no extra barrier)
    float sm = 0.0f;
    for (int p = 0; p < PP; ++p) sm += L[A_XS + p*100 + t];
    ws[WS_PRM + s*DIM + t] = sm*(1.0f/72.0f) - ws[WS_PSM + t];
  }
  // ---- QKV GEMM (this head): 18 p-tiles(4) x 12 col-tiles(6), W from global
  const float* Wt2 = ws + WS_WT2 + h*72;   // row k at Wt2[k*288 + e]
  const float SC = 0.20412414523193150f;   // 1/sqrt(24)
  if (t < 216) {
    int pt = t / 12, jt = t - pt*12;
    int p0 = pt*4, gc0 = jt*6;
    float acc[4][6];
    #pragma unroll
    for (int a = 0; a < 4; ++a)
      #pragma unroll
      for (int c = 0; c < 6; ++c) acc[a][c] = 0.0f;
    for (int k0 = 0; k0 < 96; k0 += 4) {
      float4 xv[4];
      #pragma unroll
      for (int a = 0; a < 4; ++a) xv[a] = *(const float4*)&L[A_XS + (p0+a)*100 + k0];
      const float* wr = Wt2 + (size_t)k0*288 + gc0;
      #pragma unroll
      for (int kk = 0; kk < 4; ++kk) {
        float2 w01 = *(const float2*)(wr + kk*288);
        float2 w23 = *(const float2*)(wr + kk*288 + 2);
        float2 w45 = *(const float2*)(wr + kk*288 + 4);
        float wv[6] = {w01.x, w01.y, w23.x, w23.y, w45.x, w45.y};
        #pragma unroll
        for (int a = 0; a < 4; ++a) {
          float xa = ((const float*)&xv[a])[kk];
          #pragma unroll
          for (int c = 0; c < 6; ++c) acc[a][c] += xa*wv[c];
        }
      }
    }
    int g = jt >> 2;          // 0=q,1=k,2=v
    int c0 = (jt & 3)*6;
    #pragma unroll
    for (int c = 0; c < 6; ++c) {
      int e = c0 + c;
      float bias = inb[g*96 + h*24 + e];
      #pragma unroll
      for (int a = 0; a < 4; ++a) {
        float v = acc[a][c] + bias;
        int p = p0 + a;
        if (g == 0)      L[A_QH + p*28 + e] = v*SC;
        else if (g == 1) L[A_KT + e*76 + p] = v;
        else             L[A_VT + e*76 + p] = v;
      }
    }
  }
  __syncthreads();
  // ---- S = q k^T (aliases XS, stride 76)
  for (int tile = t; tile < 648; tile += 256) {
    int qt = tile / 18, jt2 = tile - qt*18;
    int q0 = qt*2, j0 = jt2*4;
    float a0=0,a1=0,a2=0,a3=0, b0=0,b1=0,b2=0,b3=0;
    #pragma unroll
    for (int d0 = 0; d0 < 24; d0 += 4) {
      float4 q0v = *(const float4*)&L[A_QH + q0*28 + d0];
      float4 q1v = *(const float4*)&L[A_QH + (q0+1)*28 + d0];
      #pragma unroll
      for (int dd = 0; dd < 4; ++dd) {
        float4 kv = *(const float4*)&L[A_KT + (d0+dd)*76 + j0];
        float qa = ((const float*)&q0v)[dd];
        float qb = ((const float*)&q1v)[dd];
        a0 += qa*kv.x; a1 += qa*kv.y; a2 += qa*kv.z; a3 += qa*kv.w;
        b0 += qb*kv.x; b1 += qb*kv.y; b2 += qb*kv.z; b3 += qb*kv.w;
      }
    }
    *(float4*)&L[A_XS + q0*76 + j0]     = make_float4(a0,a1,a2,a3);
    *(float4*)&L[A_XS + (q0+1)*76 + j0] = make_float4(b0,b1,b2,b3);
  }
  __syncthreads();
  // ---- wave-cooperative row softmax (conflict-free, all 4 waves)
  {
    int lane = t & 63, w = t >> 6;
    for (int r = w; r < PP; r += 4) {
      float* row = &L[A_XS + r*76];
      float v0 = row[lane];
      float v1 = (lane < 8) ? row[64 + lane] : -1e30f;
      float mx = fmaxf(v0, v1);
      #pragma unroll
      for (int o = 32; o; o >>= 1) mx = fmaxf(mx, __shfl_xor(mx, o, 64));
      float e0 = __expf(v0 - mx);
      float e1 = (lane < 8) ? __expf(v1 - mx) : 0.0f;
      float sm = e0 + e1;
      #pragma unroll
      for (int o = 32; o; o >>= 1) sm += __shfl_xor(sm, o, 64);
      float inv = 1.0f/sm;
      row[lane] = e0*inv;
      if (lane < 8) row[64 + lane] = e1*inv;
    }
  }
  __syncthreads();
  // ---- O = P @ V -> global ao
  if (t < 216) {
    int qt = t / 6, dt = t - qt*6;
    int q0 = qt*2, d0 = dt*4;
    float oa[2][4];
    #pragma unroll
    for (int a = 0; a < 2; ++a)
      #pragma unroll
      for (int dd = 0; dd < 4; ++dd) oa[a][dd] = 0.0f;
    for (int j0 = 0; j0 < 72; j0 += 4) {
      float4 pv0 = *(const float4*)&L[A_XS + q0*76 + j0];
      float4 pv1 = *(const float4*)&L[A_XS + (q0+1)*76 + j0];
      #pragma unroll
      for (int dd = 0; dd < 4; ++dd) {
        float4 vv = *(const float4*)&L[A_VT + (d0+dd)*76 + j0];
        oa[0][dd] += pv0.x*vv.x + pv0.y*vv.y + pv0.z*vv.z + pv0.w*vv.w;
        oa[1][dd] += pv1.x*vv.x + pv1.y*vv.y + pv1.z*vv.z + pv1.w*vv.w;
      }
    }
    float* aob = ws + WS_AO + (size_t)aoIdx*PP*DIM;
    #pragma unroll
    for (int a = 0; a < 2; ++a)
      #pragma unroll
      for (int dd = 0; dd < 4; ++dd)
        aob[(q0+a)*DIM + h*24 + d0 + dd] = oa[a][dd];
  }
}

// -------------------- k2b: node epilogue + dynamic encoder
#define B_AO   0      // 72 x 97
#define B_LIMP 6984
#define B_IMP  7056
#define B_WSUM 7128
#define B_NB   7224
#define B_NR   7320
#define B_WB   7416
#define B_H1   7512
#define B_G1   7640
#define B_H2   7768
#define B_TOT  7832

__global__ void __launch_bounds__(128)
k2b_node(float* __restrict__ ws,
         const float* __restrict__ wo, const float* __restrict__ bo,
         const float* __restrict__ tng, const float* __restrict__ tnb,
         const float* __restrict__ dw1, const float* __restrict__ db1,
         const float* __restrict__ dg1, const float* __restrict__ dlb1,
         const float* __restrict__ dw2, const float* __restrict__ db2,
         const float* __restrict__ dg2, const float* __restrict__ dlb2,
         int s0, int aoAbs)
{
  __shared__ float L[B_TOT];
  int blk = blockIdx.x, t = threadIdx.x;
  size_t s = (size_t)s0 + blk;
  int aoIdx = aoAbs ? (int)s : blk;
  const float* aob = ws + WS_AO + (size_t)aoIdx*PP*DIM;
  for (int idx = t; idx < PP*DIM; idx += 128) {
    int p = idx/DIM, e = idx - p*DIM;
    L[B_AO + p*97 + e] = aob[idx];
  }
  if (t < 96) L[B_WB + t] = ws[WS_WBAR + t];
  __syncthreads();
  if (t < 72) {
    float sm = 0.0f;
    for (int e = 0; e < 96; ++e) sm += L[B_AO + t*97 + e]*L[B_WB + e];
    L[B_LIMP + t] = sm + ws[WS_BBAR];
  }
  __syncthreads();
  if (t < 72) {
    float mx = L[B_LIMP];
    for (int j = 1; j < 72; ++j) mx = fmaxf(mx, L[B_LIMP+j]);
    float sm = 0.0f;
    for (int j = 0; j < 72; ++j) sm += __expf(L[B_LIMP+j]-mx);
    L[B_IMP + t] = __expf(L[B_LIMP+t]-mx)/sm;
  }
  __syncthreads();
  if (t < 96) {
    float sm = 0.0f;
    for (int p = 0; p < PP; ++p) sm += L[B_IMP+p]*L[B_AO + p*97 + t];
    L[B_WSUM + t] = sm;
  }
  __syncthreads();
  if (t < 96) {
    float sm = 0.0f;
    for (int e = 0; e < 96; ++e) sm += L[B_WSUM+e]*wo[t*96 + e];
    L[B_NB + t] = sm + bo[t] + ws[WS_PRM + s*DIM + t];
  }
  __syncthreads();
  if (t < 96) {
    float mean = 0.0f;
    for (int e = 0; e < 96; ++e) mean += L[B_NB+e];
    mean *= (1.0f/96.0f);
    float var = 0.0f;
    for (int e = 0; e < 96; ++e) { float d = L[B_NB+e]-mean; var += d*d; }
    var *= (1.0f/96.0f);
    L[B_NR + t] = (L[B_NB+t]-mean)*rsqrtf(var+1e-5f)*tng[t] + tnb[t];
  }
  __syncthreads();
  {
    float sm = 0.0f;
    for (int k = 0; k < 96; ++k) sm += L[B_NR+k]*dw1[t*96 + k];
    L[B_H1 + t] = sm + db1[t];
  }
  __syncthreads();
  {
    float mean = 0.0f; for (int e = 0; e < 128; ++e) mean += L[B_H1+e];
    mean *= (1.0f/128.0f);
    float var = 0.0f; for (int e = 0; e < 128; ++e) { float d = L[B_H1+e]-mean; var += d*d; }
    var *= (1.0f/128.0f);
    float y = (L[B_H1+t]-mean)*rsqrtf(var+1e-5f)*dg1[t] + dlb1[t];
    L[B_G1 + t] = gelu_f(y);
  }
  __syncthreads();
  if (t < 64) {
    float sm = 0.0f;
    for (int k = 0; k < 128; ++k) sm += L[B_G1+k]*dw2[t*128 + k];
    L[B_H2 + t] = sm + db2[t];
  }
  __syncthreads();
  if (t < 64) {
    float mean = 0.0f; for (int e = 0; e < 64; ++e) mean += L[B_H2+e];
    mean *= (1.0f/64.0f);
    float var = 0.0f; for (int e = 0; e < 64; ++e) { float d = L[B_H2+e]-mean; var += d*d; }
    var *= (1.0f/64.0f);
    ws[WS_DEA + s*ND + t] = (L[B_H2+t]-mean)*rsqrtf(var+1e-5f)*dg2[t] + dlb2[t];
  }
}

// ------------------------------------------------ k4t: transpose de for GNN
__global__ void k4t_transpose(float* __restrict__ ws, int deoff)
{
  int bd = blockIdx.x;
  int b = bd >> 6, d = bd & 63;
  for (int m = threadIdx.x; m < NNODES; m += 256)
    ws[WS_DETG + (size_t)bd*360 + m] = ws[deoff + ((size_t)b*NNODES + m)*ND + d];
}

// --------------------------------------------------------- k4: one GNN layer
__global__ void __launch_bounds__(256)
k4_gnn(float* __restrict__ ws, int inoff, int outoff,
       const float* __restrict__ w, const float* __restrict__ bb,
       const float* __restrict__ g, const float* __restrict__ beta)
{
  __shared__ float nrow[64], lg[NNODES], pb[NNODES], aggp[4][64], aggb[64], prj[64], redv[4];
  int blk = blockIdx.x, t = threadIdx.x;
  int b = blk / NNODES;
  if (t < 64) nrow[t] = ws[inoff + (size_t)blk*ND + t];
  __syncthreads();
  const float* dg = ws + WS_DETG + (size_t)b*64*360;
  for (int m = t; m < NNODES; m += 256) {
    float sm = 0.0f;
    for (int d = 0; d < 64; ++d) sm += nrow[d]*dg[d*360 + m];
    lg[m] = sm/0.2f;
  }
  __syncthreads();
  int lane = t & 63, wv = t >> 6;
  float mx = -1e30f;
  for (int m = t; m < NNODES; m += 256) mx = fmaxf(mx, lg[m]);
  for (int o = 32; o; o >>= 1) mx = fmaxf(mx, __shfl_down(mx, o, 64));
  if (lane == 0) redv[wv] = mx;
  __syncthreads();
  float M = fmaxf(fmaxf(redv[0],redv[1]),fmaxf(redv[2],redv[3]));
  float ls = 0.0f;
  for (int m = t; m < NNODES; m += 256) { float e = __expf(lg[m]-M); pb[m] = e; ls += e; }
  for (int o = 32; o; o >>= 1) ls += __shfl_down(ls, o, 64);
  __syncthreads();
  if (lane == 0) redv[wv] = ls;
  __syncthreads();
  float inv = 1.0f/(redv[0]+redv[1]+redv[2]+redv[3]);
  for (int m = t; m < NNODES; m += 256) pb[m] *= inv;
  __syncthreads();
  {
    int d = lane, q = wv;
    float sm = 0.0f;
    for (int m = q; m < NNODES; m += 4)
      sm += pb[m]*ws[inoff + ((size_t)(b*NNODES + m))*ND + d];
    aggp[q][d] = sm;
  }
  __syncthreads();
  if (t < 64) aggb[t] = aggp[0][t]+aggp[1][t]+aggp[2][t]+aggp[3][t];
  __syncthreads();
  if (t < 64) {
    float sm = 0.0f;
    for (int d = 0; d < 64; ++d) sm += aggb[d]*w[t*64 + d];
    prj[t] = sm + bb[t];
  }
  __syncthreads();
  if (t < 64) {
    float mean = 0.0f; for (int e = 0; e < 64; ++e) mean += prj[e];
    mean *= (1.0f/64.0f);
    float var = 0.0f; for (int e = 0; e < 64; ++e) { float d = prj[e]-mean; var += d*d; }
    var *= (1.0f/64.0f);
    float y = (prj[t]-mean)*rsqrtf(var+1e-5f)*g[t] + beta[t];
    ws[outoff + (size_t)blk*ND + t] = gelu_f(y) + nrow[t];
  }
}

// ----------------------------------------------- k5: dynamic adj + top-k
__global__ void __launch_bounds__(256)
k5_dyn(const float* __restrict__ ws, const float* __restrict__ se2,
       const float* __restrict__ temp, float* __restrict__ outdyn)
{
  __shared__ float den[64], lg[NNODES], pb[NNODES], redv[4], sc[1];
  __shared__ int sel[10];
  int blk = blockIdx.x, t = threadIdx.x;
  int n = blk % NNODES;
  int bh = blk / NNODES;
  int h = bh & 3, b = bh >> 2;
  if (t < 64) den[t] = ws[WS_DEA + ((size_t)b*NNODES + n)*ND + t];
  __syncthreads();
  float tau = fminf(fmaxf(temp[h], 0.1f), 2.0f);
  const float* sp = se2 + (size_t)h*64*NNODES;
  for (int m = t; m < NNODES; m += 256) {
    float sm = 0.0f;
    for (int d = 0; d < 64; ++d) sm += den[d]*sp[d*NNODES + m];
    lg[m] = fmaxf(sm, 0.0f)/tau;
  }
  __syncthreads();
  softmax_topk_row(lg, pb, redv, sc, sel, outdyn + (size_t)blk*NNODES);
}

// ---------------------------------- k6: fusion + edge encoder + final adj
__global__ void __launch_bounds__(256)
k6_fuse(const float* __restrict__ ws, const float* __restrict__ outstat,
        const float* __restrict__ outdyn,
        const float* __restrict__ gfw, const float* __restrict__ gfb,
        const float* __restrict__ ew1, const float* __restrict__ eb1,
        const float* __restrict__ elg, const float* __restrict__ elb,
        const float* __restrict__ ew2, const float* __restrict__ eb2,
        const float* __restrict__ ew3, const float* __restrict__ eb3,
        float* __restrict__ outfin)
{
  __shared__ float sw1[64], sb1[16], slg[16], slb[16], sw2[128], sb2[8], sw3[8], sb3[1], sfw[4];
  int blk = blockIdx.x, t = threadIdx.x;
  int b = blk / NNODES, n = blk - b*NNODES;
  if (t < 64)  sw1[t] = ew1[t];
  if (t < 16)  { sb1[t] = eb1[t]; slg[t] = elg[t]; slb[t] = elb[t]; }
  if (t < 128) sw2[t] = ew2[t];
  if (t < 8)   { sb2[t] = eb2[t]; sw3[t] = ew3[t]; }
  if (t == 0)  sb3[0] = eb3[0];
  if (t < 4) {
    const float* pm = ws + WS_PRM + (size_t)blk*DIM;
    float sm = gfb[t];
    for (int e = 0; e < DIM; ++e) sm += pm[e]*gfw[t*DIM + e];
    sfw[t] = 1.0f/(1.0f+__expf(-sm));
  }
  __syncthreads();
  size_t srow = (size_t)n*NNODES;
  for (int m = t; m < NNODES; m += 256) {
    float fu[4]; float mn = 0.0f;
    #pragma unroll
    for (int hh = 0; hh < 4; ++hh) {
      float sv = outstat[(size_t)hh*NN2 + srow + m];
      float dv = outdyn[((size_t)(b*4+hh)*NNODES + n)*NNODES + m];
      float f = (1.0f - sfw[hh])*sv + sfw[hh]*dv;
      fu[hh] = f; mn += f;
    }
    mn *= 0.25f;
    float h1[16]; float m1 = 0.0f;
    #pragma unroll
    for (int j = 0; j < 16; ++j) {
      float sm = sb1[j];
      #pragma unroll
      for (int c = 0; c < 4; ++c) sm += fu[c]*sw1[j*4+c];
      h1[j] = sm; m1 += sm;
    }
    m1 *= (1.0f/16.0f);
    float v1 = 0.0f;
    #pragma unroll
    for (int j = 0; j < 16; ++j) { float d = h1[j]-m1; v1 += d*d; }
    float is1 = rsqrtf(v1*(1.0f/16.0f) + 1e-5f);
    #pragma unroll
    for (int j = 0; j < 16; ++j) h1[j] = gelu_f((h1[j]-m1)*is1*slg[j] + slb[j]);
    float h2[8];
    #pragma unroll
    for (int i = 0; i < 8; ++i) {
      float sm = sb2[i];
      #pragma unroll
      for (int j = 0; j < 16; ++j) sm += h1[j]*sw2[i*16+j];
      h2[i] = gelu_f(sm);
    }
    float ewv = sb3[0];
    #pragma unroll
    for (int i = 0; i < 8; ++i) ewv += h2[i]*sw3[i];
    float fin = (1.0f/(1.0f+__expf(-ewv)))*mn;
    outfin[(size_t)b*NN2 + srow + m] = fin;
  }
}

// ------------------------------------------------------------- launch
extern "C" void kernel_launch(void* const* d_in, const int* in_sizes, int n_in,
                              void* d_out, int out_size, void* d_ws, size_t ws_size,
                              hipStream_t stream)
{
  const float* pf   = (const float*)d_in[0];
  const float* se2  = (const float*)d_in[1];
  const float* le1  = (const float*)d_in[2];
  const float* le2  = (const float*)d_in[3];
  const float* ge1  = (const float*)d_in[4];
  const float* ge2  = (const float*)d_in[5];
  const float* temp = (const float*)d_in[6];
  const float* wi   = (const float*)d_in[7];
  const float* inb  = (const float*)d_in[8];
  const float* wo   = (const float*)d_in[9];
  const float* bo   = (const float*)d_in[10];
  const float* tng  = (const float*)d_in[11];
  const float* tnb  = (const float*)d_in[12];
  const float* dw1  = (const float*)d_in[13];
  const float* db1  = (const float*)d_in[14];
  const float* dg1  = (const float*)d_in[15];
  const float* dlb1 = (const float*)d_in[16];
  const float* dw2  = (const float*)d_in[17];
  const float* db2  = (const float*)d_in[18];
  const float* dg2  = (const float*)d_in[19];
  const float* dlb2 = (const float*)d_in[20];
  const float* pos  = (const float*)d_in[21];
  const float* g1w  = (const float*)d_in[22];
  const float* g1b  = (const float*)d_in[23];
  const float* g1g  = (const float*)d_in[24];
  const float* g1be = (const float*)d_in[25];
  const float* g2w  = (const float*)d_in[26];
  const float* g2b  = (const float*)d_in[27];
  const float* g2g  = (const float*)d_in[28];
  const float* g2be = (const float*)d_in[29];
  const float* gfw  = (const float*)d_in[30];
  const float* gfb  = (const float*)d_in[31];
  const float* ew1  = (const float*)d_in[32];
  const float* eb1  = (const float*)d_in[33];
  const float* elg  = (const float*)d_in[34];
  const float* elb  = (const float*)d_in[35];
  const float* ew2  = (const float*)d_in[36];
  const float* eb2  = (const float*)d_in[37];
  const float* ew3  = (const float*)d_in[38];
  const float* eb3  = (const float*)d_in[39];
  float* ws = (float*)d_ws;
  float* out = (float*)d_out;
  float* outfin  = out;                            // (B,N,N)
  float* outstat = out + (size_t)NB*NN2;           // (H,N,N)
  float* outdyn  = out + (size_t)(NB+NH)*NN2;      // (B,H,N,N)

  k0_setup<<<1, 256, 0, stream>>>(wi, wo, bo, pos, ws);
  k1_static<<<NH*NNODES, 256, 0, stream>>>(le1, le2, ge1, ge2, temp, outstat);

  size_t needFull = ((size_t)WS_AO + (size_t)SEQ*PP*DIM) * sizeof(float);
  if (ws_size >= needFull) {
    k2a_attn<<<SEQ*NH, 256, 0, stream>>>(pf, pos, inb, ws, 0, 1);
    k2b_node<<<SEQ, 128, 0, stream>>>(ws, wo, bo, tng, tnb,
                                      dw1, db1, dg1, dlb1, dw2, db2, dg2, dlb2, 0, 1);
  } else {
    for (int B0 = 0; B0 < NB; ++B0) {
      k2a_attn<<<NNODES*NH, 256, 0, stream>>>(pf, pos, inb, ws, B0*NNODES, 0);
      k2b_node<<<NNODES, 128, 0, stream>>>(ws, wo, bo, tng, tnb,
                                           dw1, db1, dg1, dlb1, dw2, db2, dg2, dlb2,
                                           B0*NNODES, 0);
    }
  }
  k4t_transpose<<<512, 256, 0, stream>>>(ws, WS_DEA);
  k4_gnn<<<SEQ, 256, 0, stream>>>(ws, WS_DEA, WS_DEB, g1w, g1b, g1g, g1be);
  k4t_transpose<<<512, 256, 0, stream>>>(ws, WS_DEB);
  k4_gnn<<<SEQ, 256, 0, stream>>>(ws, WS_DEB, WS_DEA, g2w, g2b, g2g, g2be);
  k5_dyn<<<NB*NH*NNODES, 256, 0, stream>>>(ws, se2, temp, outdyn);
  k6_fuse<<<SEQ, 256, 0, stream>>>(ws, outstat, outdyn, gfw, gfb,
                                   ew1, eb1, elg, elb, ew2, eb2, ew3, eb3, outfin);
}